// Round 9
// baseline (198.006 us; speedup 1.0000x reference)
//
#include <hip/hip_runtime.h>
#include <stdint.h>

typedef short short8 __attribute__((ext_vector_type(8)));
typedef float f32x4 __attribute__((ext_vector_type(4)));
typedef float f32x16 __attribute__((ext_vector_type(16)));

#define KLAM 0.003f
// B=2, H=2048, L=4096, Lk=128, N = B*L = 8192, M2 = 2H = 4096

__device__ __forceinline__ uint16_t f2bf(float f) {
  union { float f; uint32_t u; } v; v.f = f;
  uint32_t r = v.u + 0x7fffu + ((v.u >> 16) & 1u);  // RNE
  return (uint16_t)(r >> 16);
}
__device__ __forceinline__ uint32_t pack_lo(uint32_t a, uint32_t b) { return (a & 0xffffu) | (b << 16); }
__device__ __forceinline__ uint32_t pack_hi(uint32_t a, uint32_t b) { return (a >> 16) | (b & 0xffff0000u); }
__device__ __forceinline__ int swzB(int n) { return ((n & 7) ^ ((n >> 3) & 7)); }

typedef __attribute__((address_space(3))) uint32_t* lds_u32p;
typedef const __attribute__((address_space(1))) uint32_t* gbl_u32p;
__device__ __forceinline__ void gload16(const void* g, void* l) {
  __builtin_amdgcn_global_load_lds((gbl_u32p)g, (lds_u32p)l, 16, 0, 0);
}

// ---------------- K1: cast W_out (f32 [4096][2048]) -> bf16 ----------------
__global__ __launch_bounds__(256) void cast_w_kernel(const float* __restrict__ W,
                                                     uint16_t* __restrict__ Wb) {
  int i = (blockIdx.x * 256 + threadIdx.x) * 8;
  float4 f0 = *(const float4*)(W + i);
  float4 f1 = *(const float4*)(W + i + 4);
  uint4 q;
  q.x = (uint32_t)f2bf(f0.x) | ((uint32_t)f2bf(f0.y) << 16);
  q.y = (uint32_t)f2bf(f0.z) | ((uint32_t)f2bf(f0.w) << 16);
  q.z = (uint32_t)f2bf(f1.x) | ((uint32_t)f2bf(f1.y) << 16);
  q.w = (uint32_t)f2bf(f1.z) | ((uint32_t)f2bf(f1.w) << 16);
  *(uint4*)(Wb + i) = q;
}

// ------- K2: depthwise causal FIR (128 taps) via MFMA Toeplitz + u*D + exact GeLU -------
__global__ __launch_bounds__(256) void conv_gelu_kernel(const float* __restrict__ u,
                                                        const float* __restrict__ kern,
                                                        const float* __restrict__ D,
                                                        uint16_t* __restrict__ X) {
  __shared__ __align__(16) float su[4096];
  __shared__ __align__(16) uint16_t ubf[4256];
  __shared__ __align__(16) uint16_t kR[176];
  __shared__ __align__(16) uint16_t stg[4][256];

  int tid = threadIdx.x;
  int bh = blockIdx.x;
  int h = bh & 2047;
  int b = bh >> 11;
  int lane = tid & 63;
  int wv = tid >> 6;
  int ln15 = lane & 15;
  int g = lane >> 4;

  const float4* u4 = (const float4*)(u + (size_t)bh * 4096);
#pragma unroll
  for (int i = 0; i < 4; ++i) {
    float4 v = u4[i * 256 + tid];
    ((float4*)su)[i * 256 + tid] = v;
    uint2 p;
    p.x = (uint32_t)f2bf(v.x) | ((uint32_t)f2bf(v.y) << 16);
    p.y = (uint32_t)f2bf(v.z) | ((uint32_t)f2bf(v.w) << 16);
    *(uint2*)(ubf + 160 + (i * 256 + tid) * 4) = p;
  }
  if (tid < 40) { uint2 z; z.x = 0; z.y = 0; *(uint2*)(ubf + tid * 4) = z; }
  if (tid < 176) {
    int i = 159 - tid;
    uint16_t r = 0;
    if (i >= 0 && i < 128) {
      float kv = kern[h * 128 + i];
      float a = fabsf(kv) - KLAM;
      float s = (a > 0.f) ? (kv > 0.f ? a : -a) : 0.f;
      r = f2bf(s);
    }
    kR[tid] = r;
  }
  __syncthreads();

  float Dh = D[h];

  short8 bfr[5];
#pragma unroll
  for (int q = 0; q < 5; ++q) {
    int z0 = 143 - 32 * q - ln15 + 8 * g;
    union { short8 v; uint16_t s[8]; } t;
#pragma unroll
    for (int e = 0; e < 8; ++e) t.s[e] = kR[z0 + e];
    bfr[q] = t.v;
  }

#pragma unroll
  for (int it = 0; it < 4; ++it) {
    int T0 = (wv * 4 + it) * 256;
    f32x4 acc = {0.f, 0.f, 0.f, 0.f};
#pragma unroll
    for (int q = 0; q < 5; ++q) {
      const short8 a = *(const short8*)(ubf + 160 + T0 + 16 * ln15 - 16 - 32 * q + 8 * g);
      acc = __builtin_amdgcn_mfma_f32_16x16x32_bf16(a, bfr[q], acc, 0, 0, 0);
    }
#pragma unroll
    for (int r = 0; r < 4; ++r) {
      int m = 4 * g + r;
      int t = T0 + 16 * m + ln15;
      float y = acc[r] + Dh * su[t];
      float ge = 0.5f * y * (1.f + erff(y * 0.70710678118654752f));
      stg[wv][16 * m + ln15] = f2bf(ge);
    }
    uint2 v = *(uint2*)(&stg[wv][lane * 4]);
    *(uint2*)(X + (size_t)h * 8192 + (size_t)b * 4096 + T0 + lane * 4) = v;
  }
}

// ------- K2b: transpose X [2048][8192] -> XT [8192][2048] (bf16) -------
__global__ __launch_bounds__(256) void transpose_kernel(const uint16_t* __restrict__ X,
                                                        uint16_t* __restrict__ XT) {
  __shared__ uint16_t t[64][66];
  int tid = threadIdx.x;
  int bn = blockIdx.x & 127;   // n-tile
  int bk = blockIdx.x >> 7;    // k-tile
  int n0 = bn << 6, k0 = bk << 6;
  int cr = tid >> 3;           // 0..31
  int cc = (tid & 7) * 8;      // 0..56
#pragma unroll
  for (int p = 0; p < 2; ++p) {
    int kr = p * 32 + cr;
    uint4 v = *(const uint4*)(X + (size_t)(k0 + kr) * 8192 + n0 + cc);
    const uint16_t* s = (const uint16_t*)&v;
#pragma unroll
    for (int e = 0; e < 8; ++e) t[cc + e][kr] = s[e];
  }
  __syncthreads();
#pragma unroll
  for (int p = 0; p < 2; ++p) {
    int nl = p * 32 + cr;
    uint16_t d[8];
#pragma unroll
    for (int e = 0; e < 8; ++e) d[e] = t[nl][cc + e];
    *(uint4*)(XT + (size_t)(n0 + nl) * 2048 + k0 + cc) = *(uint4*)d;
  }
}

// ------- K3 v8: 256x256 GEMM + fused GLU, 32x32x16 MFMA (halved matrix-instr count) -------
// Per wave: (2 a + 2 g) m-tiles of 32 x 2 n-tiles of 32; BK=64 = 4 k-slices of 16.
// 32 MFMA/wave/K-tile in 4 phases of 8. Reads: P1 fa[2][4]+fb[2][s01] (12), P2 fb[2][s23] (4),
// P3 fg[2][4] (8), P4 none. Stage cadence + vmcnt(6) + barriers identical to v7.
__global__ __launch_bounds__(512, 2) void gemm_glu_v8(const uint16_t* __restrict__ Wb,
                                                      const uint16_t* __restrict__ XT,
                                                      const float* __restrict__ bout,
                                                      float* __restrict__ out) {
  __shared__ __align__(16) char lds[131072];  // A[2][256][64]bf16 @0, B[2][256][64] @65536

  int tid = threadIdx.x;
  int lane = tid & 63;
  int wv = tid >> 6;          // 0..7
  int wr = wv >> 2;           // 0..1  (M half)
  int wc = wv & 3;            // 0..3  (N quarter)
  int l31 = lane & 31;
  int oct = lane >> 5;        // k-octet for 32x32x16 operands

  // XCD mapping: each XCD owns 4 bn-columns (XT slice 4MB ~ one L2), sweeps bm.
  int bid = blockIdx.x;
  int xcd = bid & 7, idx = bid >> 3;
  int bn = xcd * 4 + (idx & 3);
  int bm = idx >> 2;
  int mo0 = bm * 128, n0 = bn * 256;

  // ---- staging source pointers (pre-swizzled global, linear LDS dest) ----
  int lr8 = lane >> 3;
  int sb = (((lane & 7) ^ lr8) << 4);
  const char* pAA = (const char*)Wb + (size_t)(mo0 + wv * 16 + lr8) * 4096 + sb;
  const char* pAG = (const char*)Wb + (size_t)(2048 + mo0 + wv * 16 + lr8) * 4096 + sb;
  const char* pBL = (const char*)XT + (size_t)(n0 + wv * 16 + lr8) * 4096 + sb;
  const char* pBH = (const char*)XT + (size_t)(n0 + 128 + wv * 16 + lr8) * 4096 + sb;
  uint32_t ldW = wv * 2048;

  auto stAA = [&](int buf, const char* p) {
    char* d = lds + buf * 32768 + ldW;
    gload16(p, d); gload16(p + 32768, d + 1024);
  };
  auto stAG = [&](int buf, const char* p) {
    char* d = lds + buf * 32768 + 16384 + ldW;
    gload16(p, d); gload16(p + 32768, d + 1024);
  };
  auto stBL = [&](int buf, const char* p) {
    char* d = lds + 65536 + buf * 32768 + ldW;
    gload16(p, d); gload16(p + 32768, d + 1024);
  };
  auto stBH = [&](int buf, const char* p) {
    char* d = lds + 65536 + buf * 32768 + 16384 + ldW;
    gload16(p, d); gload16(p + 32768, d + 1024);
  };

  // ---- precomputed DS read offsets (swizzle lane-invariant: row&7 == lane&7) ----
  uint32_t swz = (uint32_t)((lane & 7) << 4);
  uint32_t aoff[4], boff[4];
#pragma unroll
  for (int s = 0; s < 4; ++s) {
    uint32_t koff = (uint32_t)((s * 32 + oct * 16)) ^ swz;
    aoff[s] = (uint32_t)((wr * 64 + l31) * 128) + koff;
    boff[s] = 65536u + (uint32_t)((wc * 64 + l31) * 128) + koff;
  }

  f32x16 acc_a[2][2], acc_g[2][2];
#pragma unroll
  for (int mt = 0; mt < 2; ++mt)
#pragma unroll
    for (int nt = 0; nt < 2; ++nt) {
#pragma unroll
      for (int e = 0; e < 16; ++e) { acc_a[mt][nt][e] = 0.f; acc_g[mt][nt][e] = 0.f; }
    }

  short8 fa[2][4], fb[2][4], fg[2][4];

  // ---- prologue: tile0 full + tile1 minus BH; land tile0 (retire 8 oldest) ----
  stAA(0, pAA); stBL(0, pBL); stAG(0, pAG); stBH(0, pBH);
  stAA(1, pAA + 128); stBL(1, pBL + 128); stAG(1, pAG + 128);
  pAA += 256; pBL += 256; pAG += 256; pBH += 128;
  asm volatile("s_waitcnt vmcnt(6)" ::: "memory");
  __builtin_amdgcn_s_barrier();

  auto KTILE = [&](int t, int cur) {
    // P1: rd fa all-s (8) + fb s01 (4); stage BH(t+1)->other; lgkm(8); bar; lgkm0; MFMA a s01; bar.
#pragma unroll
    for (int mt = 0; mt < 2; ++mt)
#pragma unroll
      for (int s = 0; s < 4; ++s)
        fa[mt][s] = *(const short8*)(lds + cur * 32768 + mt * 4096 + aoff[s]);
#pragma unroll
    for (int nt = 0; nt < 2; ++nt)
#pragma unroll
      for (int s = 0; s < 2; ++s)
        fb[nt][s] = *(const short8*)(lds + cur * 32768 + nt * 4096 + boff[s]);
    if (t < 31) stBH(cur ^ 1, pBH);
    asm volatile("s_waitcnt lgkmcnt(8)" ::: "memory");
    __builtin_amdgcn_s_barrier();
    asm volatile("s_waitcnt lgkmcnt(0)" ::: "memory");
    __builtin_amdgcn_s_setprio(1);
#pragma unroll
    for (int mt = 0; mt < 2; ++mt)
#pragma unroll
      for (int nt = 0; nt < 2; ++nt)
#pragma unroll
        for (int s = 0; s < 2; ++s)
          acc_a[mt][nt] = __builtin_amdgcn_mfma_f32_32x32x16_bf16(fa[mt][s], fb[nt][s], acc_a[mt][nt], 0, 0, 0);
    __builtin_amdgcn_s_setprio(0);
    __builtin_amdgcn_s_barrier();

    // P2: rd fb s23 (4); stage AA(t+2)->cur (A-low fully read in P1); bar; lgkm0; MFMA a s23; bar.
#pragma unroll
    for (int nt = 0; nt < 2; ++nt)
#pragma unroll
      for (int s = 2; s < 4; ++s)
        fb[nt][s] = *(const short8*)(lds + cur * 32768 + nt * 4096 + boff[s]);
    if (t < 30) stAA(cur, pAA);
    __builtin_amdgcn_s_barrier();
    asm volatile("s_waitcnt lgkmcnt(0)" ::: "memory");
    __builtin_amdgcn_s_setprio(1);
#pragma unroll
    for (int mt = 0; mt < 2; ++mt)
#pragma unroll
      for (int nt = 0; nt < 2; ++nt)
#pragma unroll
        for (int s = 2; s < 4; ++s)
          acc_a[mt][nt] = __builtin_amdgcn_mfma_f32_32x32x16_bf16(fa[mt][s], fb[nt][s], acc_a[mt][nt], 0, 0, 0);
    __builtin_amdgcn_s_setprio(0);
    __builtin_amdgcn_s_barrier();

    // P3: rd fg all-s (8); stage BL(t+2)->cur (B fully read by P2); bar; lgkm0; MFMA g s01; bar.
#pragma unroll
    for (int mt = 0; mt < 2; ++mt)
#pragma unroll
      for (int s = 0; s < 4; ++s)
        fg[mt][s] = *(const short8*)(lds + cur * 32768 + 16384 + mt * 4096 + aoff[s]);
    if (t < 30) stBL(cur, pBL);
    __builtin_amdgcn_s_barrier();
    asm volatile("s_waitcnt lgkmcnt(0)" ::: "memory");
    __builtin_amdgcn_s_setprio(1);
#pragma unroll
    for (int mt = 0; mt < 2; ++mt)
#pragma unroll
      for (int nt = 0; nt < 2; ++nt)
#pragma unroll
        for (int s = 0; s < 2; ++s)
          acc_g[mt][nt] = __builtin_amdgcn_mfma_f32_32x32x16_bf16(fg[mt][s], fb[nt][s], acc_g[mt][nt], 0, 0, 0);
    __builtin_amdgcn_s_setprio(0);
    __builtin_amdgcn_s_barrier();

    // P4: stage AG(t+2)->cur (A-high fully read in P3); vmcnt; bar; MFMA g s23; bar.
    if (t < 30) {
      stAG(cur, pAG);
      asm volatile("s_waitcnt vmcnt(6)" ::: "memory");
    } else {
      asm volatile("s_waitcnt vmcnt(0)" ::: "memory");
    }
    __builtin_amdgcn_s_barrier();
    __builtin_amdgcn_s_setprio(1);
#pragma unroll
    for (int mt = 0; mt < 2; ++mt)
#pragma unroll
      for (int nt = 0; nt < 2; ++nt)
#pragma unroll
        for (int s = 2; s < 4; ++s)
          acc_g[mt][nt] = __builtin_amdgcn_mfma_f32_32x32x16_bf16(fg[mt][s], fb[nt][s], acc_g[mt][nt], 0, 0, 0);
    __builtin_amdgcn_s_setprio(0);
    __builtin_amdgcn_s_barrier();

    pAA += 128; pBL += 128; pAG += 128; pBH += 128;
  };

  for (int tt = 0; tt < 16; ++tt) {
    KTILE(2 * tt, 0);
    KTILE(2 * tt + 1, 1);
  }

  // ---- epilogue: bias + GLU; 32x32 C layout: col=l31, row=(r&3)+8*(r>>2)+4*oct ----
#pragma unroll
  for (int mt = 0; mt < 2; ++mt) {
    int obase = mo0 + wr * 64 + mt * 32 + 4 * oct;
#pragma unroll
    for (int q4 = 0; q4 < 4; ++q4) {
      float4 ba4 = *(const float4*)(bout + obase + 8 * q4);
      float4 bg4 = *(const float4*)(bout + obase + 8 * q4 + 2048);
      const float* bap = (const float*)&ba4;
      const float* bgp = (const float*)&bg4;
#pragma unroll
      for (int r0 = 0; r0 < 4; ++r0) {
        int r = q4 * 4 + r0;
        int o = obase + 8 * q4 + r0;
#pragma unroll
        for (int nt = 0; nt < 2; ++nt) {
          float av = acc_a[mt][nt][r] + bap[r0];
          float gv = acc_g[mt][nt][r] + bgp[r0];
          float res = av / (1.f + expf(-gv));
          int n = n0 + wc * 64 + nt * 32 + l31;
          out[(size_t)(n >> 12) * 8388608 + (size_t)o * 4096 + (n & 4095)] = res;
        }
      }
    }
  }
}

// ------- K3 v1 (fallback if ws too small for XT): reg-staged GEMM from X [k][n] -------
__global__ __launch_bounds__(256, 2) void gemm_glu_v1(const uint16_t* __restrict__ Wb,
                                                      const uint16_t* __restrict__ X,
                                                      const float* __restrict__ bout,
                                                      float* __restrict__ out) {
  __shared__ char lds[65536];

  int tid = threadIdx.x;
  int lane = tid & 63;
  int wv = tid >> 6;

  int bid = blockIdx.x;
  int wg = (bid & 7) * 256 + (bid >> 3);
  int bm = wg >> 6, bn = wg & 63;
  int m0 = bm * 64, n0 = bn * 128;

  int arb = tid >> 3;
  int ab = (tid & 7) * 16;
  const char* Aglob[4];
  uint32_t AwAddr[4];
#pragma unroll
  for (int i = 0; i < 4; ++i) {
    int r = i * 32 + arb;
    int o = (r < 64) ? (m0 + r) : (2048 + m0 + (r - 64));
    Aglob[i] = (const char*)Wb + (size_t)o * 4096 + ab;
    AwAddr[i] = (uint32_t)(r * 128 + (ab ^ ((r & 7) << 4)));
  }
  int n4 = (tid & 31) * 4;
  int kg = (tid >> 5) * 8;
  const char* Bglob = (const char*)X + ((size_t)kg * 8192 + (size_t)(n0 + n4)) * 2;
  uint32_t BwAddr[4];
#pragma unroll
  for (int no = 0; no < 4; ++no) {
    int n = n4 + no;
    BwAddr[no] = (uint32_t)(n * 128 + (((tid >> 5) * 16) ^ (swzB(n) << 4)));
  }

  f32x4 zero = {0.f, 0.f, 0.f, 0.f};
  f32x4 acc_a[2][4], acc_g[2][4];
#pragma unroll
  for (int mi = 0; mi < 2; ++mi)
#pragma unroll
    for (int ni = 0; ni < 4; ++ni) { acc_a[mi][ni] = zero; acc_g[mi][ni] = zero; }

  uint4 aR[4];
  uint2 bR[8];
  auto LOAD = [&](int t) {
    size_t koff = (size_t)t * 128;
#pragma unroll
    for (int i = 0; i < 4; ++i) aR[i] = *(const uint4*)(Aglob[i] + koff);
    size_t bko = (size_t)t * 64 * 16384;
#pragma unroll
    for (int i = 0; i < 8; ++i) bR[i] = *(const uint2*)(Bglob + bko + (size_t)i * 16384);
  };
  auto WRITE = [&](int buf) {
    char* A = lds + buf * 16384;
#pragma unroll
    for (int i = 0; i < 4; ++i) *(uint4*)(A + AwAddr[i]) = aR[i];
    char* Bb = lds + 32768 + buf * 16384;
    {
      uint4 q; q.x = pack_lo(bR[0].x, bR[1].x); q.y = pack_lo(bR[2].x, bR[3].x);
      q.z = pack_lo(bR[4].x, bR[5].x); q.w = pack_lo(bR[6].x, bR[7].x);
      *(uint4*)(Bb + BwAddr[0]) = q;
    }
    {
      uint4 q; q.x = pack_hi(bR[0].x, bR[1].x); q.y = pack_hi(bR[2].x, bR[3].x);
      q.z = pack_hi(bR[4].x, bR[5].x); q.w = pack_hi(bR[6].x, bR[7].x);
      *(uint4*)(Bb + BwAddr[1]) = q;
    }
    {
      uint4 q; q.x = pack_lo(bR[0].y, bR[1].y); q.y = pack_lo(bR[2].y, bR[3].y);
      q.z = pack_lo(bR[4].y, bR[5].y); q.w = pack_lo(bR[6].y, bR[7].y);
      *(uint4*)(Bb + BwAddr[2]) = q;
    }
    {
      uint4 q; q.x = pack_hi(bR[0].y, bR[1].y); q.y = pack_hi(bR[2].y, bR[3].y);
      q.z = pack_hi(bR[4].y, bR[5].y); q.w = pack_hi(bR[6].y, bR[7].y);
      *(uint4*)(Bb + BwAddr[3]) = q;
    }
  };

  LOAD(0);
  WRITE(0);
  __syncthreads();

  for (int t = 0; t < 32; ++t) {
    int cur = t & 1;
    if (t < 31) LOAD(t + 1);

    const char* A = lds + cur * 16384;
    const char* Bb = lds + 32768 + cur * 16384;
#pragma unroll
    for (int kk = 0; kk < 2; ++kk) {
      int kbyte = kk * 64 + ((lane >> 4) << 4);
      short8 fa[2], fg[2], fb[4];
#pragma unroll
      for (int mi = 0; mi < 2; ++mi) {
        int ra = (wv >> 1) * 32 + mi * 16 + (lane & 15);
        fa[mi] = *(const short8*)(A + ra * 128 + (kbyte ^ ((ra & 7) << 4)));
        int rg = 64 + ra;
        fg[mi] = *(const short8*)(A + rg * 128 + (kbyte ^ ((rg & 7) << 4)));
      }
#pragma unroll
      for (int ni = 0; ni < 4; ++ni) {
        int n = (wv & 1) * 64 + ni * 16 + (lane & 15);
        fb[ni] = *(const short8*)(Bb + n * 128 + (kbyte ^ (swzB(n) << 4)));
      }
#pragma unroll
      for (int mi = 0; mi < 2; ++mi)
#pragma unroll
        for (int ni = 0; ni < 4; ++ni) {
          acc_a[mi][ni] = __builtin_amdgcn_mfma_f32_16x16x32_bf16(fa[mi], fb[ni], acc_a[mi][ni], 0, 0, 0);
          acc_g[mi][ni] = __builtin_amdgcn_mfma_f32_16x16x32_bf16(fg[mi], fb[ni], acc_g[mi][ni], 0, 0, 0);
        }
    }

    if (t < 31) WRITE(cur ^ 1);
    __syncthreads();
  }

  int colb = n0 + (wv & 1) * 64;
#pragma unroll
  for (int mi = 0; mi < 2; ++mi) {
    int ob = m0 + (wv >> 1) * 32 + mi * 16 + ((lane >> 4) << 2);
#pragma unroll
    for (int q = 0; q < 4; ++q) {
      int o = ob + q;
      float ba = bout[o];
      float bg = bout[o + 2048];
#pragma unroll
      for (int ni = 0; ni < 4; ++ni) {
        float av = acc_a[mi][ni][q] + ba;
        float gv = acc_g[mi][ni][q] + bg;
        float res = av / (1.f + expf(-gv));
        int n = colb + ni * 16 + (lane & 15);
        out[(size_t)(n >> 12) * 8388608 + (size_t)o * 4096 + (n & 4095)] = res;
      }
    }
  }
}

extern "C" void kernel_launch(void* const* d_in, const int* in_sizes, int n_in,
                              void* d_out, int out_size, void* d_ws, size_t ws_size,
                              hipStream_t stream) {
  const float* u    = (const float*)d_in[0];
  const float* kern = (const float*)d_in[1];
  const float* D    = (const float*)d_in[2];
  const float* W    = (const float*)d_in[3];
  const float* bo   = (const float*)d_in[4];
  float* out = (float*)d_out;

  uint16_t* Wb = (uint16_t*)d_ws;                                      // 16 MB @ 0
  uint16_t* X  = (uint16_t*)((char*)d_ws + (size_t)16 * 1024 * 1024);  // 32 MB @ 16M
  uint16_t* XT = (uint16_t*)((char*)d_ws + (size_t)48 * 1024 * 1024);  // 32 MB @ 48M

  hipLaunchKernelGGL(cast_w_kernel,    dim3(4096), dim3(256), 0, stream, W, Wb);
  hipLaunchKernelGGL(conv_gelu_kernel, dim3(4096), dim3(256), 0, stream, u, kern, D, X);
  if (ws_size >= (size_t)80 * 1024 * 1024) {
    hipLaunchKernelGGL(transpose_kernel, dim3(4096), dim3(256), 0, stream, X, XT);
    hipLaunchKernelGGL(gemm_glu_v8,      dim3(512),  dim3(512), 0, stream, Wb, XT, bo, out);
  } else {
    hipLaunchKernelGGL(gemm_glu_v1,      dim3(2048), dim3(256), 0, stream, Wb, X, bo, out);
  }
}

// Round 10
// 178.210 us; speedup vs baseline: 1.1111x; 1.1111x over previous
//
#include <hip/hip_runtime.h>
#include <stdint.h>

typedef short short8 __attribute__((ext_vector_type(8)));
typedef float f32x4 __attribute__((ext_vector_type(4)));

#define KLAM 0.003f
// B=2, H=2048, L=4096, Lk=128, N = B*L = 8192, M2 = 2H = 4096

__device__ __forceinline__ uint16_t f2bf(float f) {
  union { float f; uint32_t u; } v; v.f = f;
  uint32_t r = v.u + 0x7fffu + ((v.u >> 16) & 1u);  // RNE
  return (uint16_t)(r >> 16);
}
__device__ __forceinline__ uint32_t pack_lo(uint32_t a, uint32_t b) { return (a & 0xffffu) | (b << 16); }
__device__ __forceinline__ uint32_t pack_hi(uint32_t a, uint32_t b) { return (a >> 16) | (b & 0xffff0000u); }
__device__ __forceinline__ int swzB(int n) { return ((n & 7) ^ ((n >> 3) & 7)); }

typedef __attribute__((address_space(3))) uint32_t* lds_u32p;
typedef const __attribute__((address_space(1))) uint32_t* gbl_u32p;
__device__ __forceinline__ void gload16(const void* g, void* l) {
  __builtin_amdgcn_global_load_lds((gbl_u32p)g, (lds_u32p)l, 16, 0, 0);
}

// ---------------- K1: cast W_out (f32 [4096][2048]) -> bf16 ----------------
__global__ __launch_bounds__(256) void cast_w_kernel(const float* __restrict__ W,
                                                     uint16_t* __restrict__ Wb) {
  int i = (blockIdx.x * 256 + threadIdx.x) * 8;
  float4 f0 = *(const float4*)(W + i);
  float4 f1 = *(const float4*)(W + i + 4);
  uint4 q;
  q.x = (uint32_t)f2bf(f0.x) | ((uint32_t)f2bf(f0.y) << 16);
  q.y = (uint32_t)f2bf(f0.z) | ((uint32_t)f2bf(f0.w) << 16);
  q.z = (uint32_t)f2bf(f1.x) | ((uint32_t)f2bf(f1.y) << 16);
  q.w = (uint32_t)f2bf(f1.z) | ((uint32_t)f2bf(f1.w) << 16);
  *(uint4*)(Wb + i) = q;
}

// ------- K2: depthwise causal FIR (128 taps) via MFMA Toeplitz + u*D + exact GeLU -------
__global__ __launch_bounds__(256) void conv_gelu_kernel(const float* __restrict__ u,
                                                        const float* __restrict__ kern,
                                                        const float* __restrict__ D,
                                                        uint16_t* __restrict__ X) {
  __shared__ __align__(16) float su[4096];
  __shared__ __align__(16) uint16_t ubf[4256];
  __shared__ __align__(16) uint16_t kR[176];
  __shared__ __align__(16) uint16_t stg[4][256];

  int tid = threadIdx.x;
  int bh = blockIdx.x;
  int h = bh & 2047;
  int b = bh >> 11;
  int lane = tid & 63;
  int wv = tid >> 6;
  int ln15 = lane & 15;
  int g = lane >> 4;

  const float4* u4 = (const float4*)(u + (size_t)bh * 4096);
#pragma unroll
  for (int i = 0; i < 4; ++i) {
    float4 v = u4[i * 256 + tid];
    ((float4*)su)[i * 256 + tid] = v;
    uint2 p;
    p.x = (uint32_t)f2bf(v.x) | ((uint32_t)f2bf(v.y) << 16);
    p.y = (uint32_t)f2bf(v.z) | ((uint32_t)f2bf(v.w) << 16);
    *(uint2*)(ubf + 160 + (i * 256 + tid) * 4) = p;
  }
  if (tid < 40) { uint2 z; z.x = 0; z.y = 0; *(uint2*)(ubf + tid * 4) = z; }
  if (tid < 176) {
    int i = 159 - tid;
    uint16_t r = 0;
    if (i >= 0 && i < 128) {
      float kv = kern[h * 128 + i];
      float a = fabsf(kv) - KLAM;
      float s = (a > 0.f) ? (kv > 0.f ? a : -a) : 0.f;
      r = f2bf(s);
    }
    kR[tid] = r;
  }
  __syncthreads();

  float Dh = D[h];

  short8 bfr[5];
#pragma unroll
  for (int q = 0; q < 5; ++q) {
    int z0 = 143 - 32 * q - ln15 + 8 * g;
    union { short8 v; uint16_t s[8]; } t;
#pragma unroll
    for (int e = 0; e < 8; ++e) t.s[e] = kR[z0 + e];
    bfr[q] = t.v;
  }

#pragma unroll
  for (int it = 0; it < 4; ++it) {
    int T0 = (wv * 4 + it) * 256;
    f32x4 acc = {0.f, 0.f, 0.f, 0.f};
#pragma unroll
    for (int q = 0; q < 5; ++q) {
      const short8 a = *(const short8*)(ubf + 160 + T0 + 16 * ln15 - 16 - 32 * q + 8 * g);
      acc = __builtin_amdgcn_mfma_f32_16x16x32_bf16(a, bfr[q], acc, 0, 0, 0);
    }
#pragma unroll
    for (int r = 0; r < 4; ++r) {
      int m = 4 * g + r;
      int t = T0 + 16 * m + ln15;
      float y = acc[r] + Dh * su[t];
      float ge = 0.5f * y * (1.f + erff(y * 0.70710678118654752f));
      stg[wv][16 * m + ln15] = f2bf(ge);
    }
    uint2 v = *(uint2*)(&stg[wv][lane * 4]);
    *(uint2*)(X + (size_t)h * 8192 + (size_t)b * 4096 + T0 + lane * 4) = v;
  }
}

// ------- K2b: transpose X [2048][8192] -> XT [8192][2048] (bf16) -------
__global__ __launch_bounds__(256) void transpose_kernel(const uint16_t* __restrict__ X,
                                                        uint16_t* __restrict__ XT) {
  __shared__ uint16_t t[64][66];
  int tid = threadIdx.x;
  int bn = blockIdx.x & 127;   // n-tile
  int bk = blockIdx.x >> 7;    // k-tile
  int n0 = bn << 6, k0 = bk << 6;
  int cr = tid >> 3;           // 0..31
  int cc = (tid & 7) * 8;      // 0..56
#pragma unroll
  for (int p = 0; p < 2; ++p) {
    int kr = p * 32 + cr;
    uint4 v = *(const uint4*)(X + (size_t)(k0 + kr) * 8192 + n0 + cc);
    const uint16_t* s = (const uint16_t*)&v;
#pragma unroll
    for (int e = 0; e < 8; ++e) t[cc + e][kr] = s[e];
  }
  __syncthreads();
#pragma unroll
  for (int p = 0; p < 2; ++p) {
    int nl = p * 32 + cr;
    uint16_t d[8];
#pragma unroll
    for (int e = 0; e < 8; ++e) d[e] = t[nl][cc + e];
    *(uint4*)(XT + (size_t)(n0 + nl) * 2048 + k0 + cc) = *(uint4*)d;
  }
}

// ------- K3 v9: v7 schedule WITHOUT manual lgkm fences (compiler counted waits) -------
// Hypothesis: manual lgkmcnt(0)+"memory" drains serialized DS vs MFMA. Plain loads let
// the compiler emit fine lgkmcnt(N) so MFMA starts on early-arrived fragments.
// Barriers / vmcnt(6) cadence / setprio / staging identical to v7.
__global__ __launch_bounds__(512, 2) void gemm_glu_v9(const uint16_t* __restrict__ Wb,
                                                      const uint16_t* __restrict__ XT,
                                                      const float* __restrict__ bout,
                                                      float* __restrict__ out) {
  __shared__ __align__(16) char lds[131072];  // A[2][256][64]bf16 @0, B[2][256][64] @65536

  int tid = threadIdx.x;
  int lane = tid & 63;
  int wv = tid >> 6;          // 0..7
  int wr = wv >> 2;           // 0..1  (M half)
  int wc = wv & 3;            // 0..3  (N quarter)
  int ln15 = lane & 15;
  int g16 = lane >> 4;        // 0..3

  // XCD mapping: each XCD owns 4 bn-columns (XT slice 4MB ~ one L2), sweeps bm.
  int bid = blockIdx.x;
  int xcd = bid & 7, idx = bid >> 3;
  int bn = xcd * 4 + (idx & 3);
  int bm = idx >> 2;
  int mo0 = bm * 128, n0 = bn * 256;

  // ---- staging source pointers (pre-swizzled global, linear LDS dest) ----
  int lr8 = lane >> 3;
  int sb = (((lane & 7) ^ lr8) << 4);
  const char* pAA = (const char*)Wb + (size_t)(mo0 + wv * 16 + lr8) * 4096 + sb;
  const char* pAG = (const char*)Wb + (size_t)(2048 + mo0 + wv * 16 + lr8) * 4096 + sb;
  const char* pBL = (const char*)XT + (size_t)(n0 + wv * 16 + lr8) * 4096 + sb;
  const char* pBH = (const char*)XT + (size_t)(n0 + 128 + wv * 16 + lr8) * 4096 + sb;
  uint32_t ldW = wv * 2048;

  auto stAA = [&](int buf, const char* p) {
    char* d = lds + buf * 32768 + ldW;
    gload16(p, d); gload16(p + 32768, d + 1024);
  };
  auto stAG = [&](int buf, const char* p) {
    char* d = lds + buf * 32768 + 16384 + ldW;
    gload16(p, d); gload16(p + 32768, d + 1024);
  };
  auto stBL = [&](int buf, const char* p) {
    char* d = lds + 65536 + buf * 32768 + ldW;
    gload16(p, d); gload16(p + 32768, d + 1024);
  };
  auto stBH = [&](int buf, const char* p) {
    char* d = lds + 65536 + buf * 32768 + 16384 + ldW;
    gload16(p, d); gload16(p + 32768, d + 1024);
  };

  // ---- precomputed DS read offsets (swizzle lane-invariant: row&7 == ln15&7) ----
  int sw = (ln15 & 7) << 4;
  uint32_t aoff0 = (uint32_t)((wr * 64 + ln15) * 128 + ((g16 * 16) ^ sw));
  uint32_t aoff1 = (uint32_t)((wr * 64 + ln15) * 128 + ((64 + g16 * 16) ^ sw));
  uint32_t boff0 = (uint32_t)(65536 + (wc * 64 + ln15) * 128 + ((g16 * 16) ^ sw));
  uint32_t boff1 = (uint32_t)(65536 + (wc * 64 + ln15) * 128 + ((64 + g16 * 16) ^ sw));

  f32x4 zero = {0.f, 0.f, 0.f, 0.f};
  f32x4 acc_a[4][4], acc_g[4][4];
#pragma unroll
  for (int mi = 0; mi < 4; ++mi)
#pragma unroll
    for (int ni = 0; ni < 4; ++ni) { acc_a[mi][ni] = zero; acc_g[mi][ni] = zero; }

  short8 fa[4][2], fg[4][2], fb[4][2];

  // ---- prologue: tile0 full + tile1 minus BH; land tile0 (retire 8 oldest) ----
  stAA(0, pAA); stBL(0, pBL); stAG(0, pAG); stBH(0, pBH);
  stAA(1, pAA + 128); stBL(1, pBL + 128); stAG(1, pAG + 128);
  pAA += 256; pBL += 256; pAG += 256; pBH += 128;
  asm volatile("s_waitcnt vmcnt(6)" ::: "memory");
  __builtin_amdgcn_s_barrier();

  auto KTILE = [&](int t, int cur) {
    // P1: rd fa(8)+fbLO(4); stage BH(t+1)->other; bar; MFMA a x lo (compiler waits); bar.
#pragma unroll
    for (int mi = 0; mi < 4; ++mi) {
      fa[mi][0] = *(const short8*)(lds + cur * 32768 + mi * 2048 + aoff0);
      fa[mi][1] = *(const short8*)(lds + cur * 32768 + mi * 2048 + aoff1);
    }
#pragma unroll
    for (int ni = 0; ni < 2; ++ni) {
      fb[ni][0] = *(const short8*)(lds + cur * 32768 + ni * 2048 + boff0);
      fb[ni][1] = *(const short8*)(lds + cur * 32768 + ni * 2048 + boff1);
    }
    if (t < 31) stBH(cur ^ 1, pBH);
    __builtin_amdgcn_s_barrier();
    __builtin_amdgcn_s_setprio(1);
#pragma unroll
    for (int mi = 0; mi < 4; ++mi)
#pragma unroll
      for (int ni = 0; ni < 2; ++ni)
#pragma unroll
        for (int kk = 0; kk < 2; ++kk)
          acc_a[mi][ni] = __builtin_amdgcn_mfma_f32_16x16x32_bf16(fa[mi][kk], fb[ni][kk], acc_a[mi][ni], 0, 0, 0);
    __builtin_amdgcn_s_setprio(0);
    __builtin_amdgcn_s_barrier();

    // P2: rd fbHI(4); stage AA(t+2)->cur; bar; MFMA a x hi; bar.
#pragma unroll
    for (int ni = 2; ni < 4; ++ni) {
      fb[ni][0] = *(const short8*)(lds + cur * 32768 + ni * 2048 + boff0);
      fb[ni][1] = *(const short8*)(lds + cur * 32768 + ni * 2048 + boff1);
    }
    if (t < 30) stAA(cur, pAA);
    __builtin_amdgcn_s_barrier();
    __builtin_amdgcn_s_setprio(1);
#pragma unroll
    for (int mi = 0; mi < 4; ++mi)
#pragma unroll
      for (int ni = 2; ni < 4; ++ni)
#pragma unroll
        for (int kk = 0; kk < 2; ++kk)
          acc_a[mi][ni] = __builtin_amdgcn_mfma_f32_16x16x32_bf16(fa[mi][kk], fb[ni][kk], acc_a[mi][ni], 0, 0, 0);
    __builtin_amdgcn_s_setprio(0);
    __builtin_amdgcn_s_barrier();

    // P3: rd fg(8); stage BL(t+2)->cur; bar; MFMA g x lo; bar.
#pragma unroll
    for (int mi = 0; mi < 4; ++mi) {
      fg[mi][0] = *(const short8*)(lds + cur * 32768 + 16384 + mi * 2048 + aoff0);
      fg[mi][1] = *(const short8*)(lds + cur * 32768 + 16384 + mi * 2048 + aoff1);
    }
    if (t < 30) stBL(cur, pBL);
    __builtin_amdgcn_s_barrier();
    __builtin_amdgcn_s_setprio(1);
#pragma unroll
    for (int mi = 0; mi < 4; ++mi)
#pragma unroll
      for (int ni = 0; ni < 2; ++ni)
#pragma unroll
        for (int kk = 0; kk < 2; ++kk)
          acc_g[mi][ni] = __builtin_amdgcn_mfma_f32_16x16x32_bf16(fg[mi][kk], fb[ni][kk], acc_g[mi][ni], 0, 0, 0);
    __builtin_amdgcn_s_setprio(0);
    __builtin_amdgcn_s_barrier();

    // P4: stage AG(t+2)->cur; vmcnt; bar; MFMA g x hi; bar.
    if (t < 30) {
      stAG(cur, pAG);
      asm volatile("s_waitcnt vmcnt(6)" ::: "memory");
    } else {
      asm volatile("s_waitcnt vmcnt(0)" ::: "memory");
    }
    __builtin_amdgcn_s_barrier();
    __builtin_amdgcn_s_setprio(1);
#pragma unroll
    for (int mi = 0; mi < 4; ++mi)
#pragma unroll
      for (int ni = 2; ni < 4; ++ni)
#pragma unroll
        for (int kk = 0; kk < 2; ++kk)
          acc_g[mi][ni] = __builtin_amdgcn_mfma_f32_16x16x32_bf16(fg[mi][kk], fb[ni][kk], acc_g[mi][ni], 0, 0, 0);
    __builtin_amdgcn_s_setprio(0);
    __builtin_amdgcn_s_barrier();

    pAA += 128; pBL += 128; pAG += 128; pBH += 128;
  };

  for (int tt = 0; tt < 16; ++tt) {
    KTILE(2 * tt, 0);
    KTILE(2 * tt + 1, 1);
  }

  // ---- epilogue: bias + GLU (a * sigmoid(g)), write f32 out [b][o][l]
#pragma unroll
  for (int mi = 0; mi < 4; ++mi) {
    int ob = mo0 + wr * 64 + mi * 16 + g16 * 4;
    float4 ba4 = *(const float4*)(bout + ob);
    float4 bg4 = *(const float4*)(bout + ob + 2048);
    const float* bap = (const float*)&ba4;
    const float* bgp = (const float*)&bg4;
#pragma unroll
    for (int q = 0; q < 4; ++q) {
      int o = ob + q;
#pragma unroll
      for (int ni = 0; ni < 4; ++ni) {
        float av = acc_a[mi][ni][q] + bap[q];
        float gv = acc_g[mi][ni][q] + bgp[q];
        float res = av / (1.f + expf(-gv));
        int n = n0 + wc * 64 + ni * 16 + ln15;
        out[(size_t)(n >> 12) * 8388608 + (size_t)o * 4096 + (n & 4095)] = res;
      }
    }
  }
}

// ------- K3 v1 (fallback if ws too small for XT): reg-staged GEMM from X [k][n] -------
__global__ __launch_bounds__(256, 2) void gemm_glu_v1(const uint16_t* __restrict__ Wb,
                                                      const uint16_t* __restrict__ X,
                                                      const float* __restrict__ bout,
                                                      float* __restrict__ out) {
  __shared__ char lds[65536];

  int tid = threadIdx.x;
  int lane = tid & 63;
  int wv = tid >> 6;

  int bid = blockIdx.x;
  int wg = (bid & 7) * 256 + (bid >> 3);
  int bm = wg >> 6, bn = wg & 63;
  int m0 = bm * 64, n0 = bn * 128;

  int arb = tid >> 3;
  int ab = (tid & 7) * 16;
  const char* Aglob[4];
  uint32_t AwAddr[4];
#pragma unroll
  for (int i = 0; i < 4; ++i) {
    int r = i * 32 + arb;
    int o = (r < 64) ? (m0 + r) : (2048 + m0 + (r - 64));
    Aglob[i] = (const char*)Wb + (size_t)o * 4096 + ab;
    AwAddr[i] = (uint32_t)(r * 128 + (ab ^ ((r & 7) << 4)));
  }
  int n4 = (tid & 31) * 4;
  int kg = (tid >> 5) * 8;
  const char* Bglob = (const char*)X + ((size_t)kg * 8192 + (size_t)(n0 + n4)) * 2;
  uint32_t BwAddr[4];
#pragma unroll
  for (int no = 0; no < 4; ++no) {
    int n = n4 + no;
    BwAddr[no] = (uint32_t)(n * 128 + (((tid >> 5) * 16) ^ (swzB(n) << 4)));
  }

  f32x4 zero = {0.f, 0.f, 0.f, 0.f};
  f32x4 acc_a[2][4], acc_g[2][4];
#pragma unroll
  for (int mi = 0; mi < 2; ++mi)
#pragma unroll
    for (int ni = 0; ni < 4; ++ni) { acc_a[mi][ni] = zero; acc_g[mi][ni] = zero; }

  uint4 aR[4];
  uint2 bR[8];
  auto LOAD = [&](int t) {
    size_t koff = (size_t)t * 128;
#pragma unroll
    for (int i = 0; i < 4; ++i) aR[i] = *(const uint4*)(Aglob[i] + koff);
    size_t bko = (size_t)t * 64 * 16384;
#pragma unroll
    for (int i = 0; i < 8; ++i) bR[i] = *(const uint2*)(Bglob + bko + (size_t)i * 16384);
  };
  auto WRITE = [&](int buf) {
    char* A = lds + buf * 16384;
#pragma unroll
    for (int i = 0; i < 4; ++i) *(uint4*)(A + AwAddr[i]) = aR[i];
    char* Bb = lds + 32768 + buf * 16384;
    {
      uint4 q; q.x = pack_lo(bR[0].x, bR[1].x); q.y = pack_lo(bR[2].x, bR[3].x);
      q.z = pack_lo(bR[4].x, bR[5].x); q.w = pack_lo(bR[6].x, bR[7].x);
      *(uint4*)(Bb + BwAddr[0]) = q;
    }
    {
      uint4 q; q.x = pack_hi(bR[0].x, bR[1].x); q.y = pack_hi(bR[2].x, bR[3].x);
      q.z = pack_hi(bR[4].x, bR[5].x); q.w = pack_hi(bR[6].x, bR[7].x);
      *(uint4*)(Bb + BwAddr[1]) = q;
    }
    {
      uint4 q; q.x = pack_lo(bR[0].y, bR[1].y); q.y = pack_lo(bR[2].y, bR[3].y);
      q.z = pack_lo(bR[4].y, bR[5].y); q.w = pack_lo(bR[6].y, bR[7].y);
      *(uint4*)(Bb + BwAddr[2]) = q;
    }
    {
      uint4 q; q.x = pack_hi(bR[0].y, bR[1].y); q.y = pack_hi(bR[2].y, bR[3].y);
      q.z = pack_hi(bR[4].y, bR[5].y); q.w = pack_hi(bR[6].y, bR[7].y);
      *(uint4*)(Bb + BwAddr[3]) = q;
    }
  };

  LOAD(0);
  WRITE(0);
  __syncthreads();

  for (int t = 0; t < 32; ++t) {
    int cur = t & 1;
    if (t < 31) LOAD(t + 1);

    const char* A = lds + cur * 16384;
    const char* Bb = lds + 32768 + cur * 16384;
#pragma unroll
    for (int kk = 0; kk < 2; ++kk) {
      int kbyte = kk * 64 + ((lane >> 4) << 4);
      short8 fa[2], fg[2], fb[4];
#pragma unroll
      for (int mi = 0; mi < 2; ++mi) {
        int ra = (wv >> 1) * 32 + mi * 16 + (lane & 15);
        fa[mi] = *(const short8*)(A + ra * 128 + (kbyte ^ ((ra & 7) << 4)));
        int rg = 64 + ra;
        fg[mi] = *(const short8*)(A + rg * 128 + (kbyte ^ ((rg & 7) << 4)));
      }
#pragma unroll
      for (int ni = 0; ni < 4; ++ni) {
        int n = (wv & 1) * 64 + ni * 16 + (lane & 15);
        fb[ni] = *(const short8*)(Bb + n * 128 + (kbyte ^ (swzB(n) << 4)));
      }
#pragma unroll
      for (int mi = 0; mi < 2; ++mi)
#pragma unroll
        for (int ni = 0; ni < 4; ++ni) {
          acc_a[mi][ni] = __builtin_amdgcn_mfma_f32_16x16x32_bf16(fa[mi], fb[ni], acc_a[mi][ni], 0, 0, 0);
          acc_g[mi][ni] = __builtin_amdgcn_mfma_f32_16x16x32_bf16(fg[mi], fb[ni], acc_g[mi][ni], 0, 0, 0);
        }
    }

    if (t < 31) WRITE(cur ^ 1);
    __syncthreads();
  }

  int colb = n0 + (wv & 1) * 64;
#pragma unroll
  for (int mi = 0; mi < 2; ++mi) {
    int ob = m0 + (wv >> 1) * 32 + mi * 16 + ((lane >> 4) << 2);
#pragma unroll
    for (int q = 0; q < 4; ++q) {
      int o = ob + q;
      float ba = bout[o];
      float bg = bout[o + 2048];
#pragma unroll
      for (int ni = 0; ni < 4; ++ni) {
        float av = acc_a[mi][ni][q] + ba;
        float gv = acc_g[mi][ni][q] + bg;
        float res = av / (1.f + expf(-gv));
        int n = colb + ni * 16 + (lane & 15);
        out[(size_t)(n >> 12) * 8388608 + (size_t)o * 4096 + (n & 4095)] = res;
      }
    }
  }
}

extern "C" void kernel_launch(void* const* d_in, const int* in_sizes, int n_in,
                              void* d_out, int out_size, void* d_ws, size_t ws_size,
                              hipStream_t stream) {
  const float* u    = (const float*)d_in[0];
  const float* kern = (const float*)d_in[1];
  const float* D    = (const float*)d_in[2];
  const float* W    = (const float*)d_in[3];
  const float* bo   = (const float*)d_in[4];
  float* out = (float*)d_out;

  uint16_t* Wb = (uint16_t*)d_ws;                                      // 16 MB @ 0
  uint16_t* X  = (uint16_t*)((char*)d_ws + (size_t)16 * 1024 * 1024);  // 32 MB @ 16M
  uint16_t* XT = (uint16_t*)((char*)d_ws + (size_t)48 * 1024 * 1024);  // 32 MB @ 48M

  hipLaunchKernelGGL(cast_w_kernel,    dim3(4096), dim3(256), 0, stream, W, Wb);
  hipLaunchKernelGGL(conv_gelu_kernel, dim3(4096), dim3(256), 0, stream, u, kern, D, X);
  if (ws_size >= (size_t)80 * 1024 * 1024) {
    hipLaunchKernelGGL(transpose_kernel, dim3(4096), dim3(256), 0, stream, X, XT);
    hipLaunchKernelGGL(gemm_glu_v9,      dim3(512),  dim3(512), 0, stream, Wb, XT, bo, out);
  } else {
    hipLaunchKernelGGL(gemm_glu_v1,      dim3(2048), dim3(256), 0, stream, Wb, X, bo, out);
  }
}

// Round 11
// 170.232 us; speedup vs baseline: 1.1632x; 1.0469x over previous
//
#include <hip/hip_runtime.h>
#include <stdint.h>

typedef short short8 __attribute__((ext_vector_type(8)));
typedef float f32x4 __attribute__((ext_vector_type(4)));

#define KLAM 0.003f
// B=2, H=2048, L=4096, Lk=128, N = B*L = 8192, M2 = 2H = 4096

__device__ __forceinline__ uint16_t f2bf(float f) {
  union { float f; uint32_t u; } v; v.f = f;
  uint32_t r = v.u + 0x7fffu + ((v.u >> 16) & 1u);  // RNE
  return (uint16_t)(r >> 16);
}
__device__ __forceinline__ uint32_t pack_lo(uint32_t a, uint32_t b) { return (a & 0xffffu) | (b << 16); }
__device__ __forceinline__ uint32_t pack_hi(uint32_t a, uint32_t b) { return (a >> 16) | (b & 0xffff0000u); }
__device__ __forceinline__ int swzB(int n) { return ((n & 7) ^ ((n >> 3) & 7)); }

typedef __attribute__((address_space(3))) uint32_t* lds_u32p;
typedef const __attribute__((address_space(1))) uint32_t* gbl_u32p;
__device__ __forceinline__ void gload16(const void* g, void* l) {
  __builtin_amdgcn_global_load_lds((gbl_u32p)g, (lds_u32p)l, 16, 0, 0);
}

// ---------------- K1: cast W_out (f32 [4096][2048]) -> bf16 ----------------
__global__ __launch_bounds__(256) void cast_w_kernel(const float* __restrict__ W,
                                                     uint16_t* __restrict__ Wb) {
  int i = (blockIdx.x * 256 + threadIdx.x) * 8;
  float4 f0 = *(const float4*)(W + i);
  float4 f1 = *(const float4*)(W + i + 4);
  uint4 q;
  q.x = (uint32_t)f2bf(f0.x) | ((uint32_t)f2bf(f0.y) << 16);
  q.y = (uint32_t)f2bf(f0.z) | ((uint32_t)f2bf(f0.w) << 16);
  q.z = (uint32_t)f2bf(f1.x) | ((uint32_t)f2bf(f1.y) << 16);
  q.w = (uint32_t)f2bf(f1.z) | ((uint32_t)f2bf(f1.w) << 16);
  *(uint4*)(Wb + i) = q;
}

// ------- K2: depthwise causal FIR (128 taps) via MFMA Toeplitz + u*D + exact GeLU -------
__global__ __launch_bounds__(256) void conv_gelu_kernel(const float* __restrict__ u,
                                                        const float* __restrict__ kern,
                                                        const float* __restrict__ D,
                                                        uint16_t* __restrict__ X) {
  __shared__ __align__(16) float su[4096];
  __shared__ __align__(16) uint16_t ubf[4256];
  __shared__ __align__(16) uint16_t kR[176];
  __shared__ __align__(16) uint16_t stg[4][256];

  int tid = threadIdx.x;
  int bh = blockIdx.x;
  int h = bh & 2047;
  int b = bh >> 11;
  int lane = tid & 63;
  int wv = tid >> 6;
  int ln15 = lane & 15;
  int g = lane >> 4;

  const float4* u4 = (const float4*)(u + (size_t)bh * 4096);
#pragma unroll
  for (int i = 0; i < 4; ++i) {
    float4 v = u4[i * 256 + tid];
    ((float4*)su)[i * 256 + tid] = v;
    uint2 p;
    p.x = (uint32_t)f2bf(v.x) | ((uint32_t)f2bf(v.y) << 16);
    p.y = (uint32_t)f2bf(v.z) | ((uint32_t)f2bf(v.w) << 16);
    *(uint2*)(ubf + 160 + (i * 256 + tid) * 4) = p;
  }
  if (tid < 40) { uint2 z; z.x = 0; z.y = 0; *(uint2*)(ubf + tid * 4) = z; }
  if (tid < 176) {
    int i = 159 - tid;
    uint16_t r = 0;
    if (i >= 0 && i < 128) {
      float kv = kern[h * 128 + i];
      float a = fabsf(kv) - KLAM;
      float s = (a > 0.f) ? (kv > 0.f ? a : -a) : 0.f;
      r = f2bf(s);
    }
    kR[tid] = r;
  }
  __syncthreads();

  float Dh = D[h];

  short8 bfr[5];
#pragma unroll
  for (int q = 0; q < 5; ++q) {
    int z0 = 143 - 32 * q - ln15 + 8 * g;
    union { short8 v; uint16_t s[8]; } t;
#pragma unroll
    for (int e = 0; e < 8; ++e) t.s[e] = kR[z0 + e];
    bfr[q] = t.v;
  }

#pragma unroll
  for (int it = 0; it < 4; ++it) {
    int T0 = (wv * 4 + it) * 256;
    f32x4 acc = {0.f, 0.f, 0.f, 0.f};
#pragma unroll
    for (int q = 0; q < 5; ++q) {
      const short8 a = *(const short8*)(ubf + 160 + T0 + 16 * ln15 - 16 - 32 * q + 8 * g);
      acc = __builtin_amdgcn_mfma_f32_16x16x32_bf16(a, bfr[q], acc, 0, 0, 0);
    }
#pragma unroll
    for (int r = 0; r < 4; ++r) {
      int m = 4 * g + r;
      int t = T0 + 16 * m + ln15;
      float y = acc[r] + Dh * su[t];
      float ge = 0.5f * y * (1.f + erff(y * 0.70710678118654752f));
      stg[wv][16 * m + ln15] = f2bf(ge);
    }
    uint2 v = *(uint2*)(&stg[wv][lane * 4]);
    *(uint2*)(X + (size_t)h * 8192 + (size_t)b * 4096 + T0 + lane * 4) = v;
  }
}

// ------- K2b: transpose X [2048][8192] -> XT [8192][2048] (bf16) -------
__global__ __launch_bounds__(256) void transpose_kernel(const uint16_t* __restrict__ X,
                                                        uint16_t* __restrict__ XT) {
  __shared__ uint16_t t[64][66];
  int tid = threadIdx.x;
  int bn = blockIdx.x & 127;   // n-tile
  int bk = blockIdx.x >> 7;    // k-tile
  int n0 = bn << 6, k0 = bk << 6;
  int cr = tid >> 3;           // 0..31
  int cc = (tid & 7) * 8;      // 0..56
#pragma unroll
  for (int p = 0; p < 2; ++p) {
    int kr = p * 32 + cr;
    uint4 v = *(const uint4*)(X + (size_t)(k0 + kr) * 8192 + n0 + cc);
    const uint16_t* s = (const uint16_t*)&v;
#pragma unroll
    for (int e = 0; e < 8; ++e) t[cc + e][kr] = s[e];
  }
  __syncthreads();
#pragma unroll
  for (int p = 0; p < 2; ++p) {
    int nl = p * 32 + cr;
    uint16_t d[8];
#pragma unroll
    for (int e = 0; e < 8; ++e) d[e] = t[nl][cc + e];
    *(uint4*)(XT + (size_t)(n0 + nl) * 2048 + k0 + cc) = *(uint4*)d;
  }
}

// ------- K3 v10: merged 2-phase K-tile (4 barriers/K-tile, was 8) -------
// PA: rd fa(8)+fb(8); stage BH(t+1)+AG(t+1)->other; bar; 32 MFMA a; bar.
// PB: rd fg(8); stage AA(t+2)+BL(t+2)->cur; vmcnt(4); bar; 32 MFMA g; bar.
// No manual lgkm (compiler counted waits). vmcnt(4) retires tile t+1 exactly.
__global__ __launch_bounds__(512, 2) void gemm_glu_v10(const uint16_t* __restrict__ Wb,
                                                       const uint16_t* __restrict__ XT,
                                                       const float* __restrict__ bout,
                                                       float* __restrict__ out) {
  __shared__ __align__(16) char lds[131072];  // A[2][256][64]bf16 @0, B[2][256][64] @65536

  int tid = threadIdx.x;
  int lane = tid & 63;
  int wv = tid >> 6;          // 0..7
  int wr = wv >> 2;           // 0..1  (M half)
  int wc = wv & 3;            // 0..3  (N quarter)
  int ln15 = lane & 15;
  int g16 = lane >> 4;        // 0..3

  // XCD mapping: each XCD owns 4 bn-columns (XT slice 4MB ~ one L2), sweeps bm.
  int bid = blockIdx.x;
  int xcd = bid & 7, idx = bid >> 3;
  int bn = xcd * 4 + (idx & 3);
  int bm = idx >> 2;
  int mo0 = bm * 128, n0 = bn * 256;

  // ---- staging source pointers (pre-swizzled global, linear LDS dest) ----
  int lr8 = lane >> 3;
  int sb = (((lane & 7) ^ lr8) << 4);
  const char* pAA = (const char*)Wb + (size_t)(mo0 + wv * 16 + lr8) * 4096 + sb;
  const char* pAG = (const char*)Wb + (size_t)(2048 + mo0 + wv * 16 + lr8) * 4096 + sb;
  const char* pBL = (const char*)XT + (size_t)(n0 + wv * 16 + lr8) * 4096 + sb;
  const char* pBH = (const char*)XT + (size_t)(n0 + 128 + wv * 16 + lr8) * 4096 + sb;
  uint32_t ldW = wv * 2048;

  auto stAA = [&](int buf, const char* p) {
    char* d = lds + buf * 32768 + ldW;
    gload16(p, d); gload16(p + 32768, d + 1024);
  };
  auto stAG = [&](int buf, const char* p) {
    char* d = lds + buf * 32768 + 16384 + ldW;
    gload16(p, d); gload16(p + 32768, d + 1024);
  };
  auto stBL = [&](int buf, const char* p) {
    char* d = lds + 65536 + buf * 32768 + ldW;
    gload16(p, d); gload16(p + 32768, d + 1024);
  };
  auto stBH = [&](int buf, const char* p) {
    char* d = lds + 65536 + buf * 32768 + 16384 + ldW;
    gload16(p, d); gload16(p + 32768, d + 1024);
  };

  // ---- precomputed DS read offsets (swizzle lane-invariant: row&7 == ln15&7) ----
  int sw = (ln15 & 7) << 4;
  uint32_t aoff0 = (uint32_t)((wr * 64 + ln15) * 128 + ((g16 * 16) ^ sw));
  uint32_t aoff1 = (uint32_t)((wr * 64 + ln15) * 128 + ((64 + g16 * 16) ^ sw));
  uint32_t boff0 = (uint32_t)(65536 + (wc * 64 + ln15) * 128 + ((g16 * 16) ^ sw));
  uint32_t boff1 = (uint32_t)(65536 + (wc * 64 + ln15) * 128 + ((64 + g16 * 16) ^ sw));

  f32x4 zero = {0.f, 0.f, 0.f, 0.f};
  f32x4 acc_a[4][4], acc_g[4][4];
#pragma unroll
  for (int mi = 0; mi < 4; ++mi)
#pragma unroll
    for (int ni = 0; ni < 4; ++ni) { acc_a[mi][ni] = zero; acc_g[mi][ni] = zero; }

  short8 fa[4][2], fg[4][2], fb[4][2];

  // ---- prologue: tile0 full (8 loads) + tile1 AA/BL (4 loads); land tile0 ----
  stAA(0, pAA); stBL(0, pBL); stAG(0, pAG); stBH(0, pBH);
  stAA(1, pAA + 128); stBL(1, pBL + 128);
  pAA += 256; pBL += 256; pAG += 128; pBH += 128;  // AA/BL next stage t+2, AG/BH t+1
  asm volatile("s_waitcnt vmcnt(4)" ::: "memory");
  __builtin_amdgcn_s_barrier();

  auto KTILE = [&](int t, int cur) {
    // ---- PA: rd fa + fb(all); stage BH(t+1)+AG(t+1)->other; bar; 32 MFMA a; bar
#pragma unroll
    for (int mi = 0; mi < 4; ++mi) {
      fa[mi][0] = *(const short8*)(lds + cur * 32768 + mi * 2048 + aoff0);
      fa[mi][1] = *(const short8*)(lds + cur * 32768 + mi * 2048 + aoff1);
    }
#pragma unroll
    for (int ni = 0; ni < 4; ++ni) {
      fb[ni][0] = *(const short8*)(lds + cur * 32768 + ni * 2048 + boff0);
      fb[ni][1] = *(const short8*)(lds + cur * 32768 + ni * 2048 + boff1);
    }
    if (t < 31) { stBH(cur ^ 1, pBH); stAG(cur ^ 1, pAG); }
    __builtin_amdgcn_s_barrier();
    __builtin_amdgcn_s_setprio(1);
#pragma unroll
    for (int mi = 0; mi < 4; ++mi)
#pragma unroll
      for (int ni = 0; ni < 4; ++ni)
#pragma unroll
        for (int kk = 0; kk < 2; ++kk)
          acc_a[mi][ni] = __builtin_amdgcn_mfma_f32_16x16x32_bf16(fa[mi][kk], fb[ni][kk], acc_a[mi][ni], 0, 0, 0);
    __builtin_amdgcn_s_setprio(0);
    __builtin_amdgcn_s_barrier();

    // ---- PB: rd fg; stage AA(t+2)+BL(t+2)->cur; vmcnt; bar; 32 MFMA g; bar
#pragma unroll
    for (int mi = 0; mi < 4; ++mi) {
      fg[mi][0] = *(const short8*)(lds + cur * 32768 + 16384 + mi * 2048 + aoff0);
      fg[mi][1] = *(const short8*)(lds + cur * 32768 + 16384 + mi * 2048 + aoff1);
    }
    if (t < 30) {
      stAA(cur, pAA); stBL(cur, pBL);
      asm volatile("s_waitcnt vmcnt(4)" ::: "memory");
    } else {
      asm volatile("s_waitcnt vmcnt(0)" ::: "memory");
    }
    __builtin_amdgcn_s_barrier();
    __builtin_amdgcn_s_setprio(1);
#pragma unroll
    for (int mi = 0; mi < 4; ++mi)
#pragma unroll
      for (int ni = 0; ni < 4; ++ni)
#pragma unroll
        for (int kk = 0; kk < 2; ++kk)
          acc_g[mi][ni] = __builtin_amdgcn_mfma_f32_16x16x32_bf16(fg[mi][kk], fb[ni][kk], acc_g[mi][ni], 0, 0, 0);
    __builtin_amdgcn_s_setprio(0);
    __builtin_amdgcn_s_barrier();

    pAA += 128; pBL += 128; pAG += 128; pBH += 128;
  };

  for (int tt = 0; tt < 16; ++tt) {
    KTILE(2 * tt, 0);
    KTILE(2 * tt + 1, 1);
  }

  // ---- epilogue: bias + GLU (a * sigmoid(g)), write f32 out [b][o][l]
#pragma unroll
  for (int mi = 0; mi < 4; ++mi) {
    int ob = mo0 + wr * 64 + mi * 16 + g16 * 4;
    float4 ba4 = *(const float4*)(bout + ob);
    float4 bg4 = *(const float4*)(bout + ob + 2048);
    const float* bap = (const float*)&ba4;
    const float* bgp = (const float*)&bg4;
#pragma unroll
    for (int q = 0; q < 4; ++q) {
      int o = ob + q;
#pragma unroll
      for (int ni = 0; ni < 4; ++ni) {
        float av = acc_a[mi][ni][q] + bap[q];
        float gv = acc_g[mi][ni][q] + bgp[q];
        float res = av / (1.f + expf(-gv));
        int n = n0 + wc * 64 + ni * 16 + ln15;
        out[(size_t)(n >> 12) * 8388608 + (size_t)o * 4096 + (n & 4095)] = res;
      }
    }
  }
}

// ------- K3 v1 (fallback if ws too small for XT): reg-staged GEMM from X [k][n] -------
__global__ __launch_bounds__(256, 2) void gemm_glu_v1(const uint16_t* __restrict__ Wb,
                                                      const uint16_t* __restrict__ X,
                                                      const float* __restrict__ bout,
                                                      float* __restrict__ out) {
  __shared__ char lds[65536];

  int tid = threadIdx.x;
  int lane = tid & 63;
  int wv = tid >> 6;

  int bid = blockIdx.x;
  int wg = (bid & 7) * 256 + (bid >> 3);
  int bm = wg >> 6, bn = wg & 63;
  int m0 = bm * 64, n0 = bn * 128;

  int arb = tid >> 3;
  int ab = (tid & 7) * 16;
  const char* Aglob[4];
  uint32_t AwAddr[4];
#pragma unroll
  for (int i = 0; i < 4; ++i) {
    int r = i * 32 + arb;
    int o = (r < 64) ? (m0 + r) : (2048 + m0 + (r - 64));
    Aglob[i] = (const char*)Wb + (size_t)o * 4096 + ab;
    AwAddr[i] = (uint32_t)(r * 128 + (ab ^ ((r & 7) << 4)));
  }
  int n4 = (tid & 31) * 4;
  int kg = (tid >> 5) * 8;
  const char* Bglob = (const char*)X + ((size_t)kg * 8192 + (size_t)(n0 + n4)) * 2;
  uint32_t BwAddr[4];
#pragma unroll
  for (int no = 0; no < 4; ++no) {
    int n = n4 + no;
    BwAddr[no] = (uint32_t)(n * 128 + (((tid >> 5) * 16) ^ (swzB(n) << 4)));
  }

  f32x4 zero = {0.f, 0.f, 0.f, 0.f};
  f32x4 acc_a[2][4], acc_g[2][4];
#pragma unroll
  for (int mi = 0; mi < 2; ++mi)
#pragma unroll
    for (int ni = 0; ni < 4; ++ni) { acc_a[mi][ni] = zero; acc_g[mi][ni] = zero; }

  uint4 aR[4];
  uint2 bR[8];
  auto LOAD = [&](int t) {
    size_t koff = (size_t)t * 128;
#pragma unroll
    for (int i = 0; i < 4; ++i) aR[i] = *(const uint4*)(Aglob[i] + koff);
    size_t bko = (size_t)t * 64 * 16384;
#pragma unroll
    for (int i = 0; i < 8; ++i) bR[i] = *(const uint2*)(Bglob + bko + (size_t)i * 16384);
  };
  auto WRITE = [&](int buf) {
    char* A = lds + buf * 16384;
#pragma unroll
    for (int i = 0; i < 4; ++i) *(uint4*)(A + AwAddr[i]) = aR[i];
    char* Bb = lds + 32768 + buf * 16384;
    {
      uint4 q; q.x = pack_lo(bR[0].x, bR[1].x); q.y = pack_lo(bR[2].x, bR[3].x);
      q.z = pack_lo(bR[4].x, bR[5].x); q.w = pack_lo(bR[6].x, bR[7].x);
      *(uint4*)(Bb + BwAddr[0]) = q;
    }
    {
      uint4 q; q.x = pack_hi(bR[0].x, bR[1].x); q.y = pack_hi(bR[2].x, bR[3].x);
      q.z = pack_hi(bR[4].x, bR[5].x); q.w = pack_hi(bR[6].x, bR[7].x);
      *(uint4*)(Bb + BwAddr[1]) = q;
    }
    {
      uint4 q; q.x = pack_lo(bR[0].y, bR[1].y); q.y = pack_lo(bR[2].y, bR[3].y);
      q.z = pack_lo(bR[4].y, bR[5].y); q.w = pack_lo(bR[6].y, bR[7].y);
      *(uint4*)(Bb + BwAddr[2]) = q;
    }
    {
      uint4 q; q.x = pack_hi(bR[0].y, bR[1].y); q.y = pack_hi(bR[2].y, bR[3].y);
      q.z = pack_hi(bR[4].y, bR[5].y); q.w = pack_hi(bR[6].y, bR[7].y);
      *(uint4*)(Bb + BwAddr[3]) = q;
    }
  };

  LOAD(0);
  WRITE(0);
  __syncthreads();

  for (int t = 0; t < 32; ++t) {
    int cur = t & 1;
    if (t < 31) LOAD(t + 1);

    const char* A = lds + cur * 16384;
    const char* Bb = lds + 32768 + cur * 16384;
#pragma unroll
    for (int kk = 0; kk < 2; ++kk) {
      int kbyte = kk * 64 + ((lane >> 4) << 4);
      short8 fa[2], fg[2], fb[4];
#pragma unroll
      for (int mi = 0; mi < 2; ++mi) {
        int ra = (wv >> 1) * 32 + mi * 16 + (lane & 15);
        fa[mi] = *(const short8*)(A + ra * 128 + (kbyte ^ ((ra & 7) << 4)));
        int rg = 64 + ra;
        fg[mi] = *(const short8*)(A + rg * 128 + (kbyte ^ ((rg & 7) << 4)));
      }
#pragma unroll
      for (int ni = 0; ni < 4; ++ni) {
        int n = (wv & 1) * 64 + ni * 16 + (lane & 15);
        fb[ni] = *(const short8*)(Bb + n * 128 + (kbyte ^ (swzB(n) << 4)));
      }
#pragma unroll
      for (int mi = 0; mi < 2; ++mi)
#pragma unroll
        for (int ni = 0; ni < 4; ++ni) {
          acc_a[mi][ni] = __builtin_amdgcn_mfma_f32_16x16x32_bf16(fa[mi], fb[ni], acc_a[mi][ni], 0, 0, 0);
          acc_g[mi][ni] = __builtin_amdgcn_mfma_f32_16x16x32_bf16(fg[mi], fb[ni], acc_g[mi][ni], 0, 0, 0);
        }
    }

    if (t < 31) WRITE(cur ^ 1);
    __syncthreads();
  }

  int colb = n0 + (wv & 1) * 64;
#pragma unroll
  for (int mi = 0; mi < 2; ++mi) {
    int ob = m0 + (wv >> 1) * 32 + mi * 16 + ((lane >> 4) << 2);
#pragma unroll
    for (int q = 0; q < 4; ++q) {
      int o = ob + q;
      float ba = bout[o];
      float bg = bout[o + 2048];
#pragma unroll
      for (int ni = 0; ni < 4; ++ni) {
        float av = acc_a[mi][ni][q] + ba;
        float gv = acc_g[mi][ni][q] + bg;
        float res = av / (1.f + expf(-gv));
        int n = colb + ni * 16 + (lane & 15);
        out[(size_t)(n >> 12) * 8388608 + (size_t)o * 4096 + (n & 4095)] = res;
      }
    }
  }
}

extern "C" void kernel_launch(void* const* d_in, const int* in_sizes, int n_in,
                              void* d_out, int out_size, void* d_ws, size_t ws_size,
                              hipStream_t stream) {
  const float* u    = (const float*)d_in[0];
  const float* kern = (const float*)d_in[1];
  const float* D    = (const float*)d_in[2];
  const float* W    = (const float*)d_in[3];
  const float* bo   = (const float*)d_in[4];
  float* out = (float*)d_out;

  uint16_t* Wb = (uint16_t*)d_ws;                                      // 16 MB @ 0
  uint16_t* X  = (uint16_t*)((char*)d_ws + (size_t)16 * 1024 * 1024);  // 32 MB @ 16M
  uint16_t* XT = (uint16_t*)((char*)d_ws + (size_t)48 * 1024 * 1024);  // 32 MB @ 48M

  hipLaunchKernelGGL(cast_w_kernel,    dim3(4096), dim3(256), 0, stream, W, Wb);
  hipLaunchKernelGGL(conv_gelu_kernel, dim3(4096), dim3(256), 0, stream, u, kern, D, X);
  if (ws_size >= (size_t)80 * 1024 * 1024) {
    hipLaunchKernelGGL(transpose_kernel, dim3(4096), dim3(256), 0, stream, X, XT);
    hipLaunchKernelGGL(gemm_glu_v10,     dim3(512),  dim3(512), 0, stream, Wb, XT, bo, out);
  } else {
    hipLaunchKernelGGL(gemm_glu_v1,      dim3(2048), dim3(256), 0, stream, Wb, X, bo, out);
  }
}

// Round 12
// 170.098 us; speedup vs baseline: 1.1641x; 1.0008x over previous
//
#include <hip/hip_runtime.h>
#include <stdint.h>

typedef short short8 __attribute__((ext_vector_type(8)));
typedef float f32x4 __attribute__((ext_vector_type(4)));

#define KLAM 0.003f
// B=2, H=2048, L=4096, Lk=128, N = B*L = 8192, M2 = 2H = 4096

__device__ __forceinline__ uint16_t f2bf(float f) {
  union { float f; uint32_t u; } v; v.f = f;
  uint32_t r = v.u + 0x7fffu + ((v.u >> 16) & 1u);  // RNE
  return (uint16_t)(r >> 16);
}
__device__ __forceinline__ uint32_t pack_lo(uint32_t a, uint32_t b) { return (a & 0xffffu) | (b << 16); }
__device__ __forceinline__ uint32_t pack_hi(uint32_t a, uint32_t b) { return (a >> 16) | (b & 0xffff0000u); }
__device__ __forceinline__ int swzB(int n) { return ((n & 7) ^ ((n >> 3) & 7)); }

typedef __attribute__((address_space(3))) uint32_t* lds_u32p;
typedef const __attribute__((address_space(1))) uint32_t* gbl_u32p;
__device__ __forceinline__ void gload16(const void* g, void* l) {
  __builtin_amdgcn_global_load_lds((gbl_u32p)g, (lds_u32p)l, 16, 0, 0);
}

// ------- K2 (merged): blocks 0..4095 = depthwise FIR + u*D + GeLU; 4096..8191 = cast W -------
__global__ __launch_bounds__(256) void conv_cast_kernel(const float* __restrict__ u,
                                                        const float* __restrict__ kern,
                                                        const float* __restrict__ D,
                                                        uint16_t* __restrict__ X,
                                                        const float* __restrict__ W,
                                                        uint16_t* __restrict__ Wb) {
  int bid = blockIdx.x;
  if (bid >= 4096) {
    // ---- cast W_out (f32 [4096][2048]) -> bf16
    int i = ((bid - 4096) * 256 + threadIdx.x) * 8;
    float4 f0 = *(const float4*)(W + i);
    float4 f1 = *(const float4*)(W + i + 4);
    uint4 q;
    q.x = (uint32_t)f2bf(f0.x) | ((uint32_t)f2bf(f0.y) << 16);
    q.y = (uint32_t)f2bf(f0.z) | ((uint32_t)f2bf(f0.w) << 16);
    q.z = (uint32_t)f2bf(f1.x) | ((uint32_t)f2bf(f1.y) << 16);
    q.w = (uint32_t)f2bf(f1.z) | ((uint32_t)f2bf(f1.w) << 16);
    *(uint4*)(Wb + i) = q;
    return;
  }

  __shared__ __align__(16) float su[4096];
  __shared__ __align__(16) uint16_t ubf[4256];
  __shared__ __align__(16) uint16_t kR[176];
  __shared__ __align__(16) uint16_t stg[4][256];

  int tid = threadIdx.x;
  int bh = bid;
  int h = bh & 2047;
  int b = bh >> 11;
  int lane = tid & 63;
  int wv = tid >> 6;
  int ln15 = lane & 15;
  int g = lane >> 4;

  const float4* u4 = (const float4*)(u + (size_t)bh * 4096);
#pragma unroll
  for (int i = 0; i < 4; ++i) {
    float4 v = u4[i * 256 + tid];
    ((float4*)su)[i * 256 + tid] = v;
    uint2 p;
    p.x = (uint32_t)f2bf(v.x) | ((uint32_t)f2bf(v.y) << 16);
    p.y = (uint32_t)f2bf(v.z) | ((uint32_t)f2bf(v.w) << 16);
    *(uint2*)(ubf + 160 + (i * 256 + tid) * 4) = p;
  }
  if (tid < 40) { uint2 z; z.x = 0; z.y = 0; *(uint2*)(ubf + tid * 4) = z; }
  if (tid < 176) {
    int i = 159 - tid;
    uint16_t r = 0;
    if (i >= 0 && i < 128) {
      float kv = kern[h * 128 + i];
      float a = fabsf(kv) - KLAM;
      float s = (a > 0.f) ? (kv > 0.f ? a : -a) : 0.f;
      r = f2bf(s);
    }
    kR[tid] = r;
  }
  __syncthreads();

  float Dh = D[h];

  short8 bfr[5];
#pragma unroll
  for (int q = 0; q < 5; ++q) {
    int z0 = 143 - 32 * q - ln15 + 8 * g;
    union { short8 v; uint16_t s[8]; } t;
#pragma unroll
    for (int e = 0; e < 8; ++e) t.s[e] = kR[z0 + e];
    bfr[q] = t.v;
  }

#pragma unroll
  for (int it = 0; it < 4; ++it) {
    int T0 = (wv * 4 + it) * 256;
    f32x4 acc = {0.f, 0.f, 0.f, 0.f};
#pragma unroll
    for (int q = 0; q < 5; ++q) {
      const short8 a = *(const short8*)(ubf + 160 + T0 + 16 * ln15 - 16 - 32 * q + 8 * g);
      acc = __builtin_amdgcn_mfma_f32_16x16x32_bf16(a, bfr[q], acc, 0, 0, 0);
    }
#pragma unroll
    for (int r = 0; r < 4; ++r) {
      int m = 4 * g + r;
      int t = T0 + 16 * m + ln15;
      float y = acc[r] + Dh * su[t];
      float ge = 0.5f * y * (1.f + erff(y * 0.70710678118654752f));
      stg[wv][16 * m + ln15] = f2bf(ge);
    }
    uint2 v = *(uint2*)(&stg[wv][lane * 4]);
    *(uint2*)(X + (size_t)h * 8192 + (size_t)b * 4096 + T0 + lane * 4) = v;
  }
}

// ------- K2b: transpose X [2048][8192] -> XT [8192][2048] (bf16) -------
__global__ __launch_bounds__(256) void transpose_kernel(const uint16_t* __restrict__ X,
                                                        uint16_t* __restrict__ XT) {
  __shared__ uint16_t t[64][66];
  int tid = threadIdx.x;
  int bn = blockIdx.x & 127;   // n-tile
  int bk = blockIdx.x >> 7;    // k-tile
  int n0 = bn << 6, k0 = bk << 6;
  int cr = tid >> 3;           // 0..31
  int cc = (tid & 7) * 8;      // 0..56
#pragma unroll
  for (int p = 0; p < 2; ++p) {
    int kr = p * 32 + cr;
    uint4 v = *(const uint4*)(X + (size_t)(k0 + kr) * 8192 + n0 + cc);
    const uint16_t* s = (const uint16_t*)&v;
#pragma unroll
    for (int e = 0; e < 8; ++e) t[cc + e][kr] = s[e];
  }
  __syncthreads();
#pragma unroll
  for (int p = 0; p < 2; ++p) {
    int nl = p * 32 + cr;
    uint16_t d[8];
#pragma unroll
    for (int e = 0; e < 8; ++e) d[e] = t[nl][cc + e];
    *(uint4*)(XT + (size_t)(n0 + nl) * 2048 + k0 + cc) = *(uint4*)d;
  }
}

// ------- K3 v12: v9 + P4 read-ahead of fa(t+1) (within-wave DS/MFMA overlap) -------
// P1: rd fbLO(4); stage BH(t+1); bar; MFMA a x lo (fa pre-read); bar.
// P2: rd fbHI(4); stage AA(t+2); bar; MFMA a x hi; bar.
// P3: rd fg(8);  stage BL(t+2); bar; MFMA g x lo; bar.
// P4: stage AG(t+2); vmcnt(6); bar; rd fa(t+1)<-other buf; MFMA g x hi; bar.
// No manual lgkm anywhere; compiler emits counted waits.
__global__ __launch_bounds__(512, 2) void gemm_glu_v12(const uint16_t* __restrict__ Wb,
                                                       const uint16_t* __restrict__ XT,
                                                       const float* __restrict__ bout,
                                                       float* __restrict__ out) {
  __shared__ __align__(16) char lds[131072];  // A[2][256][64]bf16 @0, B[2][256][64] @65536

  int tid = threadIdx.x;
  int lane = tid & 63;
  int wv = tid >> 6;          // 0..7
  int wr = wv >> 2;           // 0..1  (M half)
  int wc = wv & 3;            // 0..3  (N quarter)
  int ln15 = lane & 15;
  int g16 = lane >> 4;        // 0..3

  // XCD mapping: each XCD owns 4 bn-columns (XT slice 4MB ~ one L2), sweeps bm.
  int bid = blockIdx.x;
  int xcd = bid & 7, idx = bid >> 3;
  int bn = xcd * 4 + (idx & 3);
  int bm = idx >> 2;
  int mo0 = bm * 128, n0 = bn * 256;

  // ---- staging source pointers (pre-swizzled global, linear LDS dest) ----
  int lr8 = lane >> 3;
  int sb = (((lane & 7) ^ lr8) << 4);
  const char* pAA = (const char*)Wb + (size_t)(mo0 + wv * 16 + lr8) * 4096 + sb;
  const char* pAG = (const char*)Wb + (size_t)(2048 + mo0 + wv * 16 + lr8) * 4096 + sb;
  const char* pBL = (const char*)XT + (size_t)(n0 + wv * 16 + lr8) * 4096 + sb;
  const char* pBH = (const char*)XT + (size_t)(n0 + 128 + wv * 16 + lr8) * 4096 + sb;
  uint32_t ldW = wv * 2048;

  auto stAA = [&](int buf, const char* p) {
    char* d = lds + buf * 32768 + ldW;
    gload16(p, d); gload16(p + 32768, d + 1024);
  };
  auto stAG = [&](int buf, const char* p) {
    char* d = lds + buf * 32768 + 16384 + ldW;
    gload16(p, d); gload16(p + 32768, d + 1024);
  };
  auto stBL = [&](int buf, const char* p) {
    char* d = lds + 65536 + buf * 32768 + ldW;
    gload16(p, d); gload16(p + 32768, d + 1024);
  };
  auto stBH = [&](int buf, const char* p) {
    char* d = lds + 65536 + buf * 32768 + 16384 + ldW;
    gload16(p, d); gload16(p + 32768, d + 1024);
  };

  // ---- precomputed DS read offsets (swizzle lane-invariant: row&7 == ln15&7) ----
  int sw = (ln15 & 7) << 4;
  uint32_t aoff0 = (uint32_t)((wr * 64 + ln15) * 128 + ((g16 * 16) ^ sw));
  uint32_t aoff1 = (uint32_t)((wr * 64 + ln15) * 128 + ((64 + g16 * 16) ^ sw));
  uint32_t boff0 = (uint32_t)(65536 + (wc * 64 + ln15) * 128 + ((g16 * 16) ^ sw));
  uint32_t boff1 = (uint32_t)(65536 + (wc * 64 + ln15) * 128 + ((64 + g16 * 16) ^ sw));

  f32x4 zero = {0.f, 0.f, 0.f, 0.f};
  f32x4 acc_a[4][4], acc_g[4][4];
#pragma unroll
  for (int mi = 0; mi < 4; ++mi)
#pragma unroll
    for (int ni = 0; ni < 4; ++ni) { acc_a[mi][ni] = zero; acc_g[mi][ni] = zero; }

  short8 fa[4][2], fg[4][2], fb[4][2];

  auto READ_FA = [&](int buf) {
#pragma unroll
    for (int mi = 0; mi < 4; ++mi) {
      fa[mi][0] = *(const short8*)(lds + buf * 32768 + mi * 2048 + aoff0);
      fa[mi][1] = *(const short8*)(lds + buf * 32768 + mi * 2048 + aoff1);
    }
  };

  // ---- prologue: tile0 full + tile1 minus BH; land tile0; pre-read fa(0) ----
  stAA(0, pAA); stBL(0, pBL); stAG(0, pAG); stBH(0, pBH);
  stAA(1, pAA + 128); stBL(1, pBL + 128); stAG(1, pAG + 128);
  pAA += 256; pBL += 256; pAG += 256; pBH += 128;
  asm volatile("s_waitcnt vmcnt(6)" ::: "memory");
  __builtin_amdgcn_s_barrier();
  READ_FA(0);

  auto KTILE = [&](int t, int cur) {
    // P1: rd fbLO(4); stage BH(t+1)->other; bar; MFMA a x lo (fa pre-read); bar.
#pragma unroll
    for (int ni = 0; ni < 2; ++ni) {
      fb[ni][0] = *(const short8*)(lds + cur * 32768 + ni * 2048 + boff0);
      fb[ni][1] = *(const short8*)(lds + cur * 32768 + ni * 2048 + boff1);
    }
    if (t < 31) stBH(cur ^ 1, pBH);
    __builtin_amdgcn_s_barrier();
    __builtin_amdgcn_s_setprio(1);
#pragma unroll
    for (int mi = 0; mi < 4; ++mi)
#pragma unroll
      for (int ni = 0; ni < 2; ++ni)
#pragma unroll
        for (int kk = 0; kk < 2; ++kk)
          acc_a[mi][ni] = __builtin_amdgcn_mfma_f32_16x16x32_bf16(fa[mi][kk], fb[ni][kk], acc_a[mi][ni], 0, 0, 0);
    __builtin_amdgcn_s_setprio(0);
    __builtin_amdgcn_s_barrier();

    // P2: rd fbHI(4); stage AA(t+2)->cur; bar; MFMA a x hi; bar.
#pragma unroll
    for (int ni = 2; ni < 4; ++ni) {
      fb[ni][0] = *(const short8*)(lds + cur * 32768 + ni * 2048 + boff0);
      fb[ni][1] = *(const short8*)(lds + cur * 32768 + ni * 2048 + boff1);
    }
    if (t < 30) stAA(cur, pAA);
    __builtin_amdgcn_s_barrier();
    __builtin_amdgcn_s_setprio(1);
#pragma unroll
    for (int mi = 0; mi < 4; ++mi)
#pragma unroll
      for (int ni = 2; ni < 4; ++ni)
#pragma unroll
        for (int kk = 0; kk < 2; ++kk)
          acc_a[mi][ni] = __builtin_amdgcn_mfma_f32_16x16x32_bf16(fa[mi][kk], fb[ni][kk], acc_a[mi][ni], 0, 0, 0);
    __builtin_amdgcn_s_setprio(0);
    __builtin_amdgcn_s_barrier();

    // P3: rd fg(8); stage BL(t+2)->cur; bar; MFMA g x lo; bar.
#pragma unroll
    for (int mi = 0; mi < 4; ++mi) {
      fg[mi][0] = *(const short8*)(lds + cur * 32768 + 16384 + mi * 2048 + aoff0);
      fg[mi][1] = *(const short8*)(lds + cur * 32768 + 16384 + mi * 2048 + aoff1);
    }
    if (t < 30) stBL(cur, pBL);
    __builtin_amdgcn_s_barrier();
    __builtin_amdgcn_s_setprio(1);
#pragma unroll
    for (int mi = 0; mi < 4; ++mi)
#pragma unroll
      for (int ni = 0; ni < 2; ++ni)
#pragma unroll
        for (int kk = 0; kk < 2; ++kk)
          acc_g[mi][ni] = __builtin_amdgcn_mfma_f32_16x16x32_bf16(fg[mi][kk], fb[ni][kk], acc_g[mi][ni], 0, 0, 0);
    __builtin_amdgcn_s_setprio(0);
    __builtin_amdgcn_s_barrier();

    // P4: stage AG(t+2)->cur; vmcnt; bar; rd fa(t+1); MFMA g x hi; bar.
    if (t < 30) {
      stAG(cur, pAG);
      asm volatile("s_waitcnt vmcnt(6)" ::: "memory");
    } else {
      asm volatile("s_waitcnt vmcnt(0)" ::: "memory");
    }
    __builtin_amdgcn_s_barrier();
    if (t < 31) READ_FA(cur ^ 1);   // overlap with MFMA below (no dependency)
    __builtin_amdgcn_s_setprio(1);
#pragma unroll
    for (int mi = 0; mi < 4; ++mi)
#pragma unroll
      for (int ni = 2; ni < 4; ++ni)
#pragma unroll
        for (int kk = 0; kk < 2; ++kk)
          acc_g[mi][ni] = __builtin_amdgcn_mfma_f32_16x16x32_bf16(fg[mi][kk], fb[ni][kk], acc_g[mi][ni], 0, 0, 0);
    __builtin_amdgcn_s_setprio(0);
    __builtin_amdgcn_s_barrier();

    pAA += 128; pBL += 128; pAG += 128; pBH += 128;
  };

  for (int tt = 0; tt < 16; ++tt) {
    KTILE(2 * tt, 0);
    KTILE(2 * tt + 1, 1);
  }

  // ---- epilogue: bias + GLU (a * sigmoid(g)), write f32 out [b][o][l]
#pragma unroll
  for (int mi = 0; mi < 4; ++mi) {
    int ob = mo0 + wr * 64 + mi * 16 + g16 * 4;
    float4 ba4 = *(const float4*)(bout + ob);
    float4 bg4 = *(const float4*)(bout + ob + 2048);
    const float* bap = (const float*)&ba4;
    const float* bgp = (const float*)&bg4;
#pragma unroll
    for (int q = 0; q < 4; ++q) {
      int o = ob + q;
#pragma unroll
      for (int ni = 0; ni < 4; ++ni) {
        float av = acc_a[mi][ni][q] + bap[q];
        float gv = acc_g[mi][ni][q] + bgp[q];
        float res = av / (1.f + expf(-gv));
        int n = n0 + wc * 64 + ni * 16 + ln15;
        out[(size_t)(n >> 12) * 8388608 + (size_t)o * 4096 + (n & 4095)] = res;
      }
    }
  }
}

// ------- K3 v1 (fallback if ws too small for XT): reg-staged GEMM from X [k][n] -------
__global__ __launch_bounds__(256, 2) void gemm_glu_v1(const uint16_t* __restrict__ Wb,
                                                      const uint16_t* __restrict__ X,
                                                      const float* __restrict__ bout,
                                                      float* __restrict__ out) {
  __shared__ char lds[65536];

  int tid = threadIdx.x;
  int lane = tid & 63;
  int wv = tid >> 6;

  int bid = blockIdx.x;
  int wg = (bid & 7) * 256 + (bid >> 3);
  int bm = wg >> 6, bn = wg & 63;
  int m0 = bm * 64, n0 = bn * 128;

  int arb = tid >> 3;
  int ab = (tid & 7) * 16;
  const char* Aglob[4];
  uint32_t AwAddr[4];
#pragma unroll
  for (int i = 0; i < 4; ++i) {
    int r = i * 32 + arb;
    int o = (r < 64) ? (m0 + r) : (2048 + m0 + (r - 64));
    Aglob[i] = (const char*)Wb + (size_t)o * 4096 + ab;
    AwAddr[i] = (uint32_t)(r * 128 + (ab ^ ((r & 7) << 4)));
  }
  int n4 = (tid & 31) * 4;
  int kg = (tid >> 5) * 8;
  const char* Bglob = (const char*)X + ((size_t)kg * 8192 + (size_t)(n0 + n4)) * 2;
  uint32_t BwAddr[4];
#pragma unroll
  for (int no = 0; no < 4; ++no) {
    int n = n4 + no;
    BwAddr[no] = (uint32_t)(n * 128 + (((tid >> 5) * 16) ^ (swzB(n) << 4)));
  }

  f32x4 zero = {0.f, 0.f, 0.f, 0.f};
  f32x4 acc_a[2][4], acc_g[2][4];
#pragma unroll
  for (int mi = 0; mi < 2; ++mi)
#pragma unroll
    for (int ni = 0; ni < 4; ++ni) { acc_a[mi][ni] = zero; acc_g[mi][ni] = zero; }

  uint4 aR[4];
  uint2 bR[8];
  auto LOAD = [&](int t) {
    size_t koff = (size_t)t * 128;
#pragma unroll
    for (int i = 0; i < 4; ++i) aR[i] = *(const uint4*)(Aglob[i] + koff);
    size_t bko = (size_t)t * 64 * 16384;
#pragma unroll
    for (int i = 0; i < 8; ++i) bR[i] = *(const uint2*)(Bglob + bko + (size_t)i * 16384);
  };
  auto WRITE = [&](int buf) {
    char* A = lds + buf * 16384;
#pragma unroll
    for (int i = 0; i < 4; ++i) *(uint4*)(A + AwAddr[i]) = aR[i];
    char* Bb = lds + 32768 + buf * 16384;
    {
      uint4 q; q.x = pack_lo(bR[0].x, bR[1].x); q.y = pack_lo(bR[2].x, bR[3].x);
      q.z = pack_lo(bR[4].x, bR[5].x); q.w = pack_lo(bR[6].x, bR[7].x);
      *(uint4*)(Bb + BwAddr[0]) = q;
    }
    {
      uint4 q; q.x = pack_hi(bR[0].x, bR[1].x); q.y = pack_hi(bR[2].x, bR[3].x);
      q.z = pack_hi(bR[4].x, bR[5].x); q.w = pack_hi(bR[6].x, bR[7].x);
      *(uint4*)(Bb + BwAddr[1]) = q;
    }
    {
      uint4 q; q.x = pack_lo(bR[0].y, bR[1].y); q.y = pack_lo(bR[2].y, bR[3].y);
      q.z = pack_lo(bR[4].y, bR[5].y); q.w = pack_lo(bR[6].y, bR[7].y);
      *(uint4*)(Bb + BwAddr[2]) = q;
    }
    {
      uint4 q; q.x = pack_hi(bR[0].y, bR[1].y); q.y = pack_hi(bR[2].y, bR[3].y);
      q.z = pack_hi(bR[4].y, bR[5].y); q.w = pack_hi(bR[6].y, bR[7].y);
      *(uint4*)(Bb + BwAddr[3]) = q;
    }
  };

  LOAD(0);
  WRITE(0);
  __syncthreads();

  for (int t = 0; t < 32; ++t) {
    int cur = t & 1;
    if (t < 31) LOAD(t + 1);

    const char* A = lds + cur * 16384;
    const char* Bb = lds + 32768 + cur * 16384;
#pragma unroll
    for (int kk = 0; kk < 2; ++kk) {
      int kbyte = kk * 64 + ((lane >> 4) << 4);
      short8 fa[2], fg[2], fb[4];
#pragma unroll
      for (int mi = 0; mi < 2; ++mi) {
        int ra = (wv >> 1) * 32 + mi * 16 + (lane & 15);
        fa[mi] = *(const short8*)(A + ra * 128 + (kbyte ^ ((ra & 7) << 4)));
        int rg = 64 + ra;
        fg[mi] = *(const short8*)(A + rg * 128 + (kbyte ^ ((rg & 7) << 4)));
      }
#pragma unroll
      for (int ni = 0; ni < 4; ++ni) {
        int n = (wv & 1) * 64 + ni * 16 + (lane & 15);
        fb[ni] = *(const short8*)(Bb + n * 128 + (kbyte ^ (swzB(n) << 4)));
      }
#pragma unroll
      for (int mi = 0; mi < 2; ++mi)
#pragma unroll
        for (int ni = 0; ni < 4; ++ni) {
          acc_a[mi][ni] = __builtin_amdgcn_mfma_f32_16x16x32_bf16(fa[mi], fb[ni], acc_a[mi][ni], 0, 0, 0);
          acc_g[mi][ni] = __builtin_amdgcn_mfma_f32_16x16x32_bf16(fg[mi], fb[ni], acc_g[mi][ni], 0, 0, 0);
        }
    }

    if (t < 31) WRITE(cur ^ 1);
    __syncthreads();
  }

  int colb = n0 + (wv & 1) * 64;
#pragma unroll
  for (int mi = 0; mi < 2; ++mi) {
    int ob = m0 + (wv >> 1) * 32 + mi * 16 + ((lane >> 4) << 2);
#pragma unroll
    for (int q = 0; q < 4; ++q) {
      int o = ob + q;
      float ba = bout[o];
      float bg = bout[o + 2048];
#pragma unroll
      for (int ni = 0; ni < 4; ++ni) {
        float av = acc_a[mi][ni][q] + ba;
        float gv = acc_g[mi][ni][q] + bg;
        float res = av / (1.f + expf(-gv));
        int n = colb + ni * 16 + (lane & 15);
        out[(size_t)(n >> 12) * 8388608 + (size_t)o * 4096 + (n & 4095)] = res;
      }
    }
  }
}

extern "C" void kernel_launch(void* const* d_in, const int* in_sizes, int n_in,
                              void* d_out, int out_size, void* d_ws, size_t ws_size,
                              hipStream_t stream) {
  const float* u    = (const float*)d_in[0];
  const float* kern = (const float*)d_in[1];
  const float* D    = (const float*)d_in[2];
  const float* W    = (const float*)d_in[3];
  const float* bo   = (const float*)d_in[4];
  float* out = (float*)d_out;

  uint16_t* Wb = (uint16_t*)d_ws;                                      // 16 MB @ 0
  uint16_t* X  = (uint16_t*)((char*)d_ws + (size_t)16 * 1024 * 1024);  // 32 MB @ 16M
  uint16_t* XT = (uint16_t*)((char*)d_ws + (size_t)48 * 1024 * 1024);  // 32 MB @ 48M

  hipLaunchKernelGGL(conv_cast_kernel, dim3(8192), dim3(256), 0, stream, u, kern, D, X, W, Wb);
  if (ws_size >= (size_t)80 * 1024 * 1024) {
    hipLaunchKernelGGL(transpose_kernel, dim3(4096), dim3(256), 0, stream, X, XT);
    hipLaunchKernelGGL(gemm_glu_v12,     dim3(512),  dim3(512), 0, stream, Wb, XT, bo, out);
  } else {
    hipLaunchKernelGGL(gemm_glu_v1,      dim3(2048), dim3(256), 0, stream, Wb, X, bo, out);
  }
}